// Round 6
// baseline (737.310 us; speedup 1.0000x reference)
//
#include <hip/hip_runtime.h>

typedef _Float16 f16;
typedef __attribute__((ext_vector_type(8))) _Float16 f16x8;
typedef __attribute__((ext_vector_type(4))) _Float16 f16x4;
typedef __attribute__((ext_vector_type(4))) float f32x4;

#define MFMA16(a, b, c) __builtin_amdgcn_mfma_f32_16x16x32_f16(a, b, c, 0, 0, 0)

#define SCALE_F 0.17677669529663687f
#define NHEAD 12
#define NTOK 49
#define NBW 2048

#define SB() __builtin_amdgcn_s_barrier()
#define SCHEDB() __builtin_amdgcn_sched_barrier(0)
#define WAITV4() asm volatile("s_waitcnt vmcnt(4)" ::: "memory")
#define WAITV0() asm volatile("s_waitcnt vmcnt(0)" ::: "memory")
#define WAITV8() asm volatile("s_waitcnt vmcnt(8)" ::: "memory")
#define WAITL0() asm volatile("s_waitcnt lgkmcnt(0)" ::: "memory")

// ---------------------------------------------------------------------------
// cast f32 -> f16 (vectorized x4)
// ---------------------------------------------------------------------------
__global__ void cast_f32_to_f16(const float* __restrict__ in, f16* __restrict__ out, int n4) {
    int i0 = blockIdx.x * 256 + threadIdx.x;
    int stride = gridDim.x * 256;
    for (int i = i0; i < n4; i += stride) {
        f32x4 v = ((const f32x4*)in)[i];
        f16x4 o;
#pragma unroll
        for (int e = 0; e < 4; ++e) o[e] = (f16)v[e];
        ((f16x4*)out)[i] = o;
    }
}

// ---------------------------------------------------------------------------
// precompute BM[w4][h][64][64] = rpb-bias + mask, padded with -1e30
// ---------------------------------------------------------------------------
__global__ void prep_bm(const float* __restrict__ rpb, const int* __restrict__ rel_idx,
                        const float* __restrict__ mask, float* __restrict__ bm) {
    int blk = blockIdx.x;  // w4*12 + h
    int w4 = blk / NHEAD, h = blk - w4 * NHEAD;
    for (int idx = threadIdx.x; idx < 4096; idx += 64) {
        int r = idx >> 6, c = idx & 63;
        float v = -1e30f;
        if (r < NTOK && c < NTOK)
            v = rpb[rel_idx[r * NTOK + c] * NHEAD + h] + mask[(w4 * NTOK + r) * NTOK + c];
        bm[(size_t)blk * 4096 + idx] = v;
    }
}

// ---------------------------------------------------------------------------
// 8-phase 256x256 GEMM (T2+T3+T4+T5): C[M][N] = A[M][K=384] @ B[N][K]^T + bias
// 512 threads (8 waves: 2M x 4N), BK=64, double-buffered 128KB LDS,
// counted vmcnt(4) at phases 4/8 only, XOR chunk swizzle, masked N-tail.
// M must be a multiple of 256. B-row over-reads past Nreal stay inside d_ws
// (buffers are contiguous); affected cols are masked in the epilogue.
// ---------------------------------------------------------------------------
template <typename OUT_T>
__global__ __launch_bounds__(512, 2) void gemm8(const f16* __restrict__ A, const f16* __restrict__ B,
                                                const float* __restrict__ bias, OUT_T* __restrict__ C,
                                                int Nreal, int ldc) {
    __shared__ __align__(16) f16 LA[2][256][64];
    __shared__ __align__(16) f16 LB[2][256][64];

    const int nwg = gridDim.x * gridDim.y;
    int wg = blockIdx.y * gridDim.x + blockIdx.x;
    wg = (wg & 7) * (nwg >> 3) + (wg >> 3);
    const int m0 = (wg / gridDim.x) * 256;
    const int n0 = (wg % gridDim.x) * 256;

    const int tid = threadIdx.x;
    const int w = tid >> 6, l = tid & 63;
    const int wm = w >> 2, wn = w & 3;
    const int lr = l & 15, lg = l >> 4;

    // staging: waves 0-3 stage A rows (w&3)*64.., waves 4-7 stage B rows
    const int smat = (w >= 4);
    const int srow_base = (w & 3) * 64;
    const int lrow = l >> 3;   // 0..7
    const int lchunk = l & 7;  // 0..7

    auto STAGE = [&](int kt, int j0) {
#pragma unroll
        for (int jj = 0; jj < 2; ++jj) {
            int row0 = srow_base + (j0 + jj) * 8;
            int r = row0 + lrow;
            int c = lchunk ^ (r & 7);
            const f16* src;
            f16* dst;
            if (smat == 0) {
                src = A + (size_t)(m0 + r) * 384 + kt * 64 + c * 8;
                dst = &LA[kt & 1][row0][0];
            } else {
                // no clamp: over-read past Nreal stays inside d_ws; masked at store
                src = B + (size_t)(n0 + r) * 384 + kt * 64 + c * 8;
                dst = &LB[kt & 1][row0][0];
            }
            __builtin_amdgcn_global_load_lds((const __attribute__((address_space(1))) void*)src,
                                             (__attribute__((address_space(3))) void*)dst, 16, 0, 0);
        }
    };

    auto LDAf = [&](int d, int mi, int ks) {
        int r = wm * 128 + mi * 16 + lr;
        int c = (ks * 4 + lg) ^ (r & 7);
        return *(const f16x8*)&LA[d][r][c * 8];
    };
    auto LDBf = [&](int d, int ni, int ks) {
        int r = wn * 64 + ni * 16 + lr;
        int c = (ks * 4 + lg) ^ (r & 7);
        return *(const f16x8*)&LB[d][r][c * 8];
    };

    f32x4 acc[8][4] = {};
    f16x8 a[8][2], b[4][2];

    // prologue: stage kt0 + kt1 fully, wait kt0, barrier
    STAGE(0, 0); STAGE(0, 2); STAGE(0, 4); STAGE(0, 6);
    STAGE(1, 0); STAGE(1, 2); STAGE(1, 4); STAGE(1, 6);
    WAITV8();
    SB();
    SCHEDB();

    // half-iteration: 4 phases consuming dbuf D; stages: phases 1-2 tail of
    // SE_KT (j4..7), phases 3-4 head of SM_KT (j0..3); WV at phase-4 end.
    auto half_iter = [&](int D, int sekt, bool sec, int smkt, bool smc, int wv) {
        // ---- phase 1: reads (a0-3, b0-1) + stage
#pragma unroll
        for (int mi = 0; mi < 4; ++mi) { a[mi][0] = LDAf(D, mi, 0); a[mi][1] = LDAf(D, mi, 1); }
#pragma unroll
        for (int ni = 0; ni < 2; ++ni) { b[ni][0] = LDBf(D, ni, 0); b[ni][1] = LDBf(D, ni, 1); }
        if (sec) STAGE(sekt, 4);
        SB();
        __builtin_amdgcn_s_setprio(1);
#pragma unroll
        for (int mi = 0; mi < 4; ++mi)
#pragma unroll
            for (int ni = 0; ni < 2; ++ni) {
                acc[mi][ni] = MFMA16(a[mi][0], b[ni][0], acc[mi][ni]);
                acc[mi][ni] = MFMA16(a[mi][1], b[ni][1], acc[mi][ni]);
            }
        __builtin_amdgcn_s_setprio(0);
        SB();
        // ---- phase 2: reads (a4-7, b2-3) + stage
#pragma unroll
        for (int mi = 4; mi < 8; ++mi) { a[mi][0] = LDAf(D, mi, 0); a[mi][1] = LDAf(D, mi, 1); }
#pragma unroll
        for (int ni = 2; ni < 4; ++ni) { b[ni][0] = LDBf(D, ni, 0); b[ni][1] = LDBf(D, ni, 1); }
        if (sec) STAGE(sekt, 6);
        SB();
        __builtin_amdgcn_s_setprio(1);
#pragma unroll
        for (int mi = 0; mi < 4; ++mi)
#pragma unroll
            for (int ni = 2; ni < 4; ++ni) {
                acc[mi][ni] = MFMA16(a[mi][0], b[ni][0], acc[mi][ni]);
                acc[mi][ni] = MFMA16(a[mi][1], b[ni][1], acc[mi][ni]);
            }
        __builtin_amdgcn_s_setprio(0);
        WAITL0();  // all dbuf-D reads landed in regs before anyone overwrites D
        SB();
        // ---- phase 3: stage head of SM_KT
        if (smc) STAGE(smkt, 0);
        SB();
        __builtin_amdgcn_s_setprio(1);
#pragma unroll
        for (int mi = 4; mi < 8; ++mi)
#pragma unroll
            for (int ni = 0; ni < 2; ++ni) {
                acc[mi][ni] = MFMA16(a[mi][0], b[ni][0], acc[mi][ni]);
                acc[mi][ni] = MFMA16(a[mi][1], b[ni][1], acc[mi][ni]);
            }
        __builtin_amdgcn_s_setprio(0);
        SB();
        // ---- phase 4: stage + counted flip wait
        if (smc) STAGE(smkt, 2);
        SB();
        __builtin_amdgcn_s_setprio(1);
#pragma unroll
        for (int mi = 4; mi < 8; ++mi)
#pragma unroll
            for (int ni = 2; ni < 4; ++ni) {
                acc[mi][ni] = MFMA16(a[mi][0], b[ni][0], acc[mi][ni]);
                acc[mi][ni] = MFMA16(a[mi][1], b[ni][1], acc[mi][ni]);
            }
        __builtin_amdgcn_s_setprio(0);
        if (wv == 4) WAITV4();
        else if (wv == 0) WAITV0();
        SB();
        SCHEDB();
    };

#pragma unroll
    for (int t = 0; t < 3; ++t) {
        const int kt0 = 2 * t, kt1 = 2 * t + 1;
        // phases 1-4: compute kt0 (dbuf0); stage kt1-tail (unless prologue-staged) + kt0+2 head
        half_iter(0, kt1, t > 0, kt0 + 2, kt0 + 2 < 6, (t < 2) ? 4 : 0);
        // phases 5-8: compute kt1 (dbuf1); stage kt0+2 tail + kt1+2 head
        half_iter(1, kt0 + 2, kt0 + 2 < 6, kt1 + 2, kt1 + 2 < 6, (t < 2) ? 4 : -1);
    }

    // epilogue: C/D layout col=lane&15, row=(lane>>4)*4+reg [m89]; masked N-tail
#pragma unroll
    for (int mi = 0; mi < 8; ++mi) {
#pragma unroll
        for (int ni = 0; ni < 4; ++ni) {
            int col = n0 + wn * 64 + ni * 16 + lr;
            if (col < Nreal) {
                float bv = bias[col];
#pragma unroll
                for (int reg = 0; reg < 4; ++reg) {
                    int row = m0 + wm * 128 + mi * 16 + lg * 4 + reg;
                    C[(size_t)row * ldc + col] = (OUT_T)(acc[mi][ni][reg] + bv);
                }
            }
        }
    }
}

// ---------------------------------------------------------------------------
// fused attention: one block (1 wave) per (window, head)
// QK^T via MFMA (frags straight from global), V fragments prefetched into
// registers right after QK^T (T14), wave-parallel softmax, P through
// XOR-swizzled LDS, MFMA PV per stream. Over-reads (j>=49) hit P=0.
// ---------------------------------------------------------------------------
__global__ __launch_bounds__(64) void attn_kernel(const f16* __restrict__ qkv,
                                                  const f16* __restrict__ vse,
                                                  const float* __restrict__ bm_all,
                                                  f16* __restrict__ att_se, f16* __restrict__ att_de) {
    __shared__ __align__(16) f16 Ps[64 * 64];  // P, swizzled

    const int bh = blockIdx.x;
    const int b = bh / NHEAD, h = bh - b * NHEAD;
    const int l = threadIdx.x;
    const int lr = l & 15, lg = l >> 4;
    const size_t wbase = (size_t)b * NTOK;

    f16x8 qa[4], kb[4];
#pragma unroll
    for (int mi = 0; mi < 4; ++mi)
        qa[mi] = *(const f16x8*)(qkv + (wbase + 16 * mi + lr) * 1152 + h * 32 + lg * 8);
#pragma unroll
    for (int ni = 0; ni < 4; ++ni)
        kb[ni] = *(const f16x8*)(qkv + (wbase + 16 * ni + lr) * 1152 + 384 + h * 32 + lg * 8);

    const f32x4 zero4 = {0.f, 0.f, 0.f, 0.f};
    f32x4 S[4][4];
    __builtin_amdgcn_s_setprio(1);
#pragma unroll
    for (int mi = 0; mi < 4; ++mi)
#pragma unroll
        for (int ni = 0; ni < 4; ++ni)
            S[mi][ni] = MFMA16(qa[mi], kb[ni], zero4);
    __builtin_amdgcn_s_setprio(0);

    // T14: issue all V-fragment gathers now; they complete under the softmax
    f16x8 vbr[2][2][2];  // [stream][ks][ni]
#pragma unroll
    for (int s = 0; s < 2; ++s) {
        const f16* vbase = s ? (qkv + wbase * 1152 + 768 + h * 32) : (vse + wbase * 384 + h * 32);
        const int RS = s ? 1152 : 384;
#pragma unroll
        for (int ks = 0; ks < 2; ++ks)
#pragma unroll
            for (int ni = 0; ni < 2; ++ni) {
                const f16* p = vbase + (size_t)(8 * lg + 32 * ks) * RS + 16 * ni + lr;
#pragma unroll
                for (int e = 0; e < 8; ++e) vbr[s][ks][ni][e] = p[(size_t)e * RS];
            }
    }

    const float* bmp = bm_all + (size_t)((b & 3) * NHEAD + h) * 4096;
#pragma unroll
    for (int mi = 0; mi < 4; ++mi) {
#pragma unroll
        for (int reg = 0; reg < 4; ++reg) {
            int r = 16 * mi + 4 * lg + reg;
            float v[4];
#pragma unroll
            for (int ni = 0; ni < 4; ++ni)
                v[ni] = S[mi][ni][reg] * SCALE_F + bmp[(r << 6) + 16 * ni + lr];
            float mx = fmaxf(fmaxf(v[0], v[1]), fmaxf(v[2], v[3]));
#pragma unroll
            for (int off = 1; off < 16; off <<= 1) mx = fmaxf(mx, __shfl_xor(mx, off));
            float e[4];
            float sm = 0.f;
#pragma unroll
            for (int ni = 0; ni < 4; ++ni) {
                e[ni] = __expf(v[ni] - mx);
                sm += e[ni];
            }
#pragma unroll
            for (int off = 1; off < 16; off <<= 1) sm += __shfl_xor(sm, off);
            float inv = 1.f / sm;
#pragma unroll
            for (int ni = 0; ni < 4; ++ni)
                Ps[(r << 6) + ((16 * ni + lr) ^ ((r & 7) << 3))] = (f16)(e[ni] * inv);
        }
    }
    __syncthreads();

#pragma unroll
    for (int s = 0; s < 2; ++s) {
        f32x4 o[4][2] = {};
#pragma unroll
        for (int ks = 0; ks < 2; ++ks) {
            f16x8 pa[4];
#pragma unroll
            for (int mi = 0; mi < 4; ++mi) {
                int r = 16 * mi + lr;
                pa[mi] = *(const f16x8*)(Ps + (r << 6) + ((8 * lg + 32 * ks) ^ ((r & 7) << 3)));
            }
            __builtin_amdgcn_s_setprio(1);
#pragma unroll
            for (int ni = 0; ni < 2; ++ni)
#pragma unroll
                for (int mi = 0; mi < 4; ++mi) o[mi][ni] = MFMA16(pa[mi], vbr[s][ks][ni], o[mi][ni]);
            __builtin_amdgcn_s_setprio(0);
        }
        f16* dst = s ? att_de : att_se;
#pragma unroll
        for (int mi = 0; mi < 4; ++mi) {
#pragma unroll
            for (int reg = 0; reg < 4; ++reg) {
                int r = 16 * mi + 4 * lg + reg;
                if (r < NTOK) {
#pragma unroll
                    for (int ni = 0; ni < 2; ++ni)
                        dst[(wbase + r) * 384 + h * 32 + 16 * ni + lr] = (f16)o[mi][ni][reg];
                }
            }
        }
    }
}

// ---------------------------------------------------------------------------
extern "C" void kernel_launch(void* const* d_in, const int* in_sizes, int n_in,
                              void* d_out, int out_size, void* d_ws, size_t ws_size,
                              hipStream_t stream) {
    const float* se = (const float*)d_in[0];
    const float* de = (const float*)d_in[1];
    const float* mask = (const float*)d_in[2];
    const float* w_v_se = (const float*)d_in[3];
    const float* b_v_se = (const float*)d_in[4];
    const float* w_qkv = (const float*)d_in[5];
    const float* b_qkv = (const float*)d_in[6];
    const float* w_proj_se = (const float*)d_in[7];
    const float* b_proj_se = (const float*)d_in[8];
    const float* w_proj_de = (const float*)d_in[9];
    const float* b_proj_de = (const float*)d_in[10];
    const float* rpb = (const float*)d_in[11];
    const int* rel_idx = (const int*)d_in[12];

    const size_t SE_ELEMS = (size_t)NBW * NTOK * 384;  // 38,535,168

    char* ws = (char*)d_ws;
    f16* de_h = (f16*)(ws);                // A of qkv GEMM; reused as att_se
    f16* se_h = (f16*)(ws + 77070336);     // A of vse GEMM; reused as att_de
    f16* qkv_h = (f16*)(ws + 154140672);   // (100352, 1152)
    f16* vse_h = (f16*)(ws + 385351680);   // (100352, 384)
    f16* wqkv_h = (f16*)(ws + 462422016);
    f16* wvse_h = (f16*)(ws + 463306752);
    f16* wpse_h = (f16*)(ws + 463601664);
    f16* wpde_h = (f16*)(ws + 463896576);
    float* bm = (float*)(ws + 464191488);

    auto cast = [&](const float* in, f16* out, size_t n) {
        int n4 = (int)(n / 4);
        int blocks = (n4 + 255) / 256;
        if (blocks > 2048) blocks = 2048;
        cast_f32_to_f16<<<blocks, 256, 0, stream>>>(in, out, n4);
    };
    cast(de, de_h, SE_ELEMS);
    cast(se, se_h, SE_ELEMS);
    cast(w_qkv, wqkv_h, (size_t)1152 * 384);
    cast(w_v_se, wvse_h, (size_t)384 * 384);
    cast(w_proj_se, wpse_h, (size_t)384 * 384);
    cast(w_proj_de, wpde_h, (size_t)384 * 384);

    prep_bm<<<48, 64, 0, stream>>>(rpb, rel_idx, mask, bm);

    // qkv = de @ w_qkv^T + b   (M=100352, N=1152): 5 N-tiles (tail masked)
    gemm8<f16><<<dim3(5, 392), 512, 0, stream>>>(de_h, wqkv_h, b_qkv, qkv_h, 1152, 1152);
    // v_se = se @ w_v_se^T + b (N=384): 2 N-tiles
    gemm8<f16><<<dim3(2, 392), 512, 0, stream>>>(se_h, wvse_h, b_v_se, vse_h, 384, 384);

    // attention: att_se -> de_h region, att_de -> se_h region
    attn_kernel<<<NBW * NHEAD, 64, 0, stream>>>(qkv_h, vse_h, bm, de_h, se_h);

    // projections straight into d_out (f32)
    gemm8<float><<<dim3(2, 392), 512, 0, stream>>>(de_h, wpse_h, b_proj_se, (float*)d_out, 384, 384);
    gemm8<float><<<dim3(2, 392), 512, 0, stream>>>(se_h, wpde_h, b_proj_de, (float*)d_out + SE_ELEMS, 384, 384);
}

// Round 7
// 697.613 us; speedup vs baseline: 1.0569x; 1.0569x over previous
//
#include <hip/hip_runtime.h>

typedef _Float16 f16;
typedef __attribute__((ext_vector_type(8))) _Float16 f16x8;
typedef __attribute__((ext_vector_type(4))) _Float16 f16x4;
typedef __attribute__((ext_vector_type(4))) float f32x4;

#define MFMA16(a, b, c) __builtin_amdgcn_mfma_f32_16x16x32_f16(a, b, c, 0, 0, 0)

#define SCALE_F 0.17677669529663687f
#define NHEAD 12
#define NTOK 49
#define NBW 2048
#define VTJ 56  // j-dim of transposed V buffers

#define SB() __builtin_amdgcn_s_barrier()
#define SCHEDB() __builtin_amdgcn_sched_barrier(0)
#define WAITL0() asm volatile("s_waitcnt lgkmcnt(0)" ::: "memory")

// ---------------------------------------------------------------------------
// all four weight casts in one launch (f32 -> f16, x4 vectors)
// ---------------------------------------------------------------------------
__global__ void cast_weights(const float* __restrict__ wqkv, const float* __restrict__ wvse,
                             const float* __restrict__ wpse, const float* __restrict__ wpde,
                             f16* o_qkv, f16* o_vse, f16* o_pse, f16* o_pde) {
    int i = blockIdx.x * 256 + threadIdx.x;  // x4 groups; total 221184
    if (i >= 221184) return;
    const float* src;
    f16* dst;
    int off;
    if (i < 110592) { src = wqkv; dst = o_qkv; off = i; }
    else if (i < 147456) { src = wvse; dst = o_vse; off = i - 110592; }
    else if (i < 184320) { src = wpse; dst = o_pse; off = i - 147456; }
    else { src = wpde; dst = o_pde; off = i - 184320; }
    f32x4 v = ((const f32x4*)src)[off];
    f16x4 o;
#pragma unroll
    for (int e = 0; e < 4; ++e) o[e] = (f16)v[e];
    ((f16x4*)dst)[off] = o;
}

// ---------------------------------------------------------------------------
// precompute BM[w4][h][64][64] = rpb-bias + mask, padded with -1e30
// ---------------------------------------------------------------------------
__global__ void prep_bm(const float* __restrict__ rpb, const int* __restrict__ rel_idx,
                        const float* __restrict__ mask, float* __restrict__ bm) {
    int blk = blockIdx.x;  // w4*12 + h
    int w4 = blk / NHEAD, h = blk - w4 * NHEAD;
    for (int idx = threadIdx.x; idx < 4096; idx += 64) {
        int r = idx >> 6, c = idx & 63;
        float v = -1e30f;
        if (r < NTOK && c < NTOK)
            v = rpb[rel_idx[r * NTOK + c] * NHEAD + h] + mask[(w4 * NTOK + r) * NTOK + c];
        bm[(size_t)blk * 4096 + idx] = v;
    }
}

// ---------------------------------------------------------------------------
// GEMM: C[M][N] = A[M][K=384] @ B[N][K]^T + bias[N]
// 128x128 tile, BK=64, 256 threads (4 waves, 2x2), T1 XCD swizzle.
// A is reg-staged (f32 with fused cast when A_F32, else f16) with a 1-deep
// prefetch pipeline: A-regs for k+1 load during compute of k; raw s_barrier +
// counted vmcnt so the prefetch survives the flip (T4). B via global_load_lds.
// EPI: 0 = normal store to C (ldc); 1 = qkv split (cols<768 -> C with q-cols
// pre-scaled by SCALE_F, cols>=768 -> VT transposed); 2 = all cols -> VT.
// ---------------------------------------------------------------------------
template <int EPI, bool A_F32, typename OUT_T>
__global__ __launch_bounds__(256) void gemm_bt(const void* __restrict__ Av, const f16* __restrict__ B,
                                               const float* __restrict__ bias, OUT_T* __restrict__ C,
                                               f16* __restrict__ VT, int N, int ldc) {
    __shared__ __align__(16) f16 As[128 * 64];
    __shared__ __align__(16) f16 Bs[128 * 64];
    const int nwg = gridDim.x * gridDim.y;
    int wg = blockIdx.y * gridDim.x + blockIdx.x;
    wg = (wg & 7) * (nwg >> 3) + (wg >> 3);
    const int m0 = (wg / gridDim.x) * 128, n0 = (wg % gridDim.x) * 128;
    const int tid = threadIdx.x;
    const int w = tid >> 6, l = tid & 63;
    const int wm = w >> 1, wn = w & 1;
    const int lr = l & 15, lg = l >> 4;
    const int sp = l & 7;
    const int lrow = l >> 3;

    f32x4 acc[4][4] = {};
    f32x4 t0[4], t1[4];  // A f32 prefetch regs
    f16x8 tf[4];         // A f16 prefetch regs

    auto LOADA = [&](int kt) {
#pragma unroll
        for (int it = 0; it < 4; ++it) {
            int row = w * 32 + it * 8 + lrow;
            if constexpr (A_F32) {
                const float* g = (const float*)Av + (size_t)(m0 + row) * 384 + kt * 64 + sp * 8;
                t0[it] = *(const f32x4*)g;
                t1[it] = *(const f32x4*)(g + 4);
            } else {
                tf[it] = *(const f16x8*)((const f16*)Av + (size_t)(m0 + row) * 384 + kt * 64 + sp * 8);
            }
        }
    };
    auto CVTWRITE = [&]() {
#pragma unroll
        for (int it = 0; it < 4; ++it) {
            int row = w * 32 + it * 8 + lrow;
            f16x8 hx;
            if constexpr (A_F32) {
#pragma unroll
                for (int e = 0; e < 4; ++e) { hx[e] = (f16)t0[it][e]; hx[e + 4] = (f16)t1[it][e]; }
            } else {
                hx = tf[it];
            }
            *(f16x8*)(As + row * 64 + (sp ^ (row & 7)) * 8) = hx;
        }
    };
    auto STAGEB = [&](int kt) {
#pragma unroll
        for (int it = 0; it < 4; ++it) {
            int row = w * 32 + it * 8 + lrow;
            int gchunk = sp ^ (row & 7);
            const f16* gB = B + (size_t)(n0 + row) * 384 + kt * 64 + gchunk * 8;
            f16* lB = Bs + (w * 32 + it * 8) * 64;  // wave-uniform; HW adds lane*16B
            __builtin_amdgcn_global_load_lds((const __attribute__((address_space(1))) void*)gB,
                                             (__attribute__((address_space(3))) void*)lB, 16, 0, 0);
        }
    };

    LOADA(0);
#pragma unroll
    for (int t = 0; t < 6; ++t) {
        WAITL0();
        SB();  // barrier1: everyone's LDS reads of tile t-1 are done
        SCHEDB();
        CVTWRITE();            // compiler waits A-regs(t)
        STAGEB(t);             // 4 vmem
        if (t < 5) LOADA(t + 1);  // 8 (f32) or 4 (f16) vmem, stays in flight
        WAITL0();              // ds_writes visible
        if (t < 5) {
            if constexpr (A_F32) asm volatile("s_waitcnt vmcnt(8)" ::: "memory");
            else asm volatile("s_waitcnt vmcnt(4)" ::: "memory");
        } else {
            asm volatile("s_waitcnt vmcnt(0)" ::: "memory");
        }
        SB();  // barrier2: tile t fully staged
        SCHEDB();
#pragma unroll
        for (int ks = 0; ks < 2; ++ks) {
            f16x8 af[4], bfr[4];
#pragma unroll
            for (int mi = 0; mi < 4; ++mi) {
                int r = 64 * wm + 16 * mi + lr;
                int chunk = (lg + 4 * ks) ^ (r & 7);
                af[mi] = *(const f16x8*)(As + r * 64 + chunk * 8);
            }
#pragma unroll
            for (int ni = 0; ni < 4; ++ni) {
                int r = 64 * wn + 16 * ni + lr;
                int chunk = (lg + 4 * ks) ^ (r & 7);
                bfr[ni] = *(const f16x8*)(Bs + r * 64 + chunk * 8);
            }
            __builtin_amdgcn_s_setprio(1);
#pragma unroll
            for (int mi = 0; mi < 4; ++mi)
#pragma unroll
                for (int ni = 0; ni < 4; ++ni)
                    acc[mi][ni] = MFMA16(af[mi], bfr[ni], acc[mi][ni]);
            __builtin_amdgcn_s_setprio(0);
        }
    }

    // epilogue: C/D layout col=lane&15, row=(lane>>4)*4+reg [m89]
#pragma unroll
    for (int mi = 0; mi < 4; ++mi) {
#pragma unroll
        for (int ni = 0; ni < 4; ++ni) {
            int col = n0 + 64 * wn + 16 * ni + lr;
            float bv = bias[col];
#pragma unroll
            for (int reg = 0; reg < 4; ++reg) {
                int row = m0 + 64 * wm + 16 * mi + 4 * lg + reg;
                float v = acc[mi][ni][reg] + bv;
                if constexpr (EPI == 0) {
                    C[(size_t)row * ldc + col] = (OUT_T)v;
                } else if constexpr (EPI == 1) {
                    if (col < 768) {
                        if (col < 384) v *= SCALE_F;  // fold softmax scale into Q
                        C[(size_t)row * 768 + col] = (OUT_T)v;
                    } else {
                        int c2 = col - 768;
                        int b = row / 49, j = row - b * 49;
                        VT[((size_t)b * NHEAD + (c2 >> 5)) * (32 * VTJ) + (c2 & 31) * VTJ + j] = (f16)v;
                    }
                } else {
                    int b = row / 49, j = row - b * 49;
                    VT[((size_t)b * NHEAD + (col >> 5)) * (32 * VTJ) + (col & 31) * VTJ + j] = (f16)v;
                }
            }
        }
    }
}

// ---------------------------------------------------------------------------
// fused attention: 128 threads = 2 independent waves, each owns one (window,
// head). QK^T from qk_h (stride 768, Q pre-scaled), V fragments via 16B
// vector loads from transposed Vt buffers (T14-prefetched under softmax),
// wave-parallel softmax, P through wave-private XOR-swizzled LDS (no
// __syncthreads — per-wave lgkmcnt ordering only).
// ---------------------------------------------------------------------------
__global__ __launch_bounds__(128) void attn_kernel(const f16* __restrict__ qk,
                                                   const f16* __restrict__ vse_t,
                                                   const f16* __restrict__ vde_t,
                                                   const float* __restrict__ bm_all,
                                                   f16* __restrict__ att_se, f16* __restrict__ att_de) {
    __shared__ __align__(16) f16 Ps[2][64 * 64];  // per-wave P, swizzled

    const int wv = threadIdx.x >> 6;
    const int l = threadIdx.x & 63;
    const int bh = blockIdx.x * 2 + wv;
    const int b = bh / NHEAD, h = bh - b * NHEAD;
    const int lr = l & 15, lg = l >> 4;
    const size_t wbase = (size_t)b * NTOK;
    f16* P = Ps[wv];

    // QK^T fragments (over-read past last window lands in vse_t region — safe)
    f16x8 qa[4], kb[4];
#pragma unroll
    for (int mi = 0; mi < 4; ++mi)
        qa[mi] = *(const f16x8*)(qk + (wbase + 16 * mi + lr) * 768 + h * 32 + lg * 8);
#pragma unroll
    for (int ni = 0; ni < 4; ++ni)
        kb[ni] = *(const f16x8*)(qk + (wbase + 16 * ni + lr) * 768 + 384 + h * 32 + lg * 8);

    const f32x4 zero4 = {0.f, 0.f, 0.f, 0.f};
    f32x4 S[4][4];
    __builtin_amdgcn_s_setprio(1);
#pragma unroll
    for (int mi = 0; mi < 4; ++mi)
#pragma unroll
        for (int ni = 0; ni < 4; ++ni)
            S[mi][ni] = MFMA16(qa[mi], kb[ni], zero4);
    __builtin_amdgcn_s_setprio(0);

    // T14: prefetch V fragments (16B vector loads from transposed buffers);
    // they complete under the softmax. j>=49 slots multiply P=0 (any finite).
    f16x8 vbr[2][2][2];  // [stream][ks][ni]
#pragma unroll
    for (int s = 0; s < 2; ++s) {
        const f16* vt = (s ? vde_t : vse_t) + (size_t)bh * (32 * VTJ);
#pragma unroll
        for (int ks = 0; ks < 2; ++ks)
#pragma unroll
            for (int ni = 0; ni < 2; ++ni) {
                int j0 = 8 * lg + 32 * ks;
                if (j0 == 56) j0 = 48;  // VTJ=56: top slot re-reads j=48 block (P=0 there)
                vbr[s][ks][ni] = *(const f16x8*)(vt + (16 * ni + lr) * VTJ + j0);
            }
    }

    // softmax (Q pre-scaled; bias+mask from precomputed table)
    const float* bmp = bm_all + (size_t)((b & 3) * NHEAD + h) * 4096;
#pragma unroll
    for (int mi = 0; mi < 4; ++mi) {
#pragma unroll
        for (int reg = 0; reg < 4; ++reg) {
            int r = 16 * mi + 4 * lg + reg;
            float v[4];
#pragma unroll
            for (int ni = 0; ni < 4; ++ni)
                v[ni] = S[mi][ni][reg] + bmp[(r << 6) + 16 * ni + lr];
            float mx = fmaxf(fmaxf(v[0], v[1]), fmaxf(v[2], v[3]));
#pragma unroll
            for (int off = 1; off < 16; off <<= 1) mx = fmaxf(mx, __shfl_xor(mx, off));
            float e[4];
            float sm = 0.f;
#pragma unroll
            for (int ni = 0; ni < 4; ++ni) {
                e[ni] = __expf(v[ni] - mx);
                sm += e[ni];
            }
#pragma unroll
            for (int off = 1; off < 16; off <<= 1) sm += __shfl_xor(sm, off);
            float inv = 1.f / sm;
#pragma unroll
            for (int ni = 0; ni < 4; ++ni)
                P[(r << 6) + ((16 * ni + lr) ^ ((r & 7) << 3))] = (f16)(e[ni] * inv);
        }
    }
    WAITL0();  // wave-private P: per-wave LDS ordering is enough
    SCHEDB();

#pragma unroll
    for (int s = 0; s < 2; ++s) {
        f32x4 o[4][2] = {};
#pragma unroll
        for (int ks = 0; ks < 2; ++ks) {
            f16x8 pa[4];
#pragma unroll
            for (int mi = 0; mi < 4; ++mi) {
                int r = 16 * mi + lr;
                pa[mi] = *(const f16x8*)(P + (r << 6) + ((8 * lg + 32 * ks) ^ ((r & 7) << 3)));
            }
            __builtin_amdgcn_s_setprio(1);
#pragma unroll
            for (int ni = 0; ni < 2; ++ni)
#pragma unroll
                for (int mi = 0; mi < 4; ++mi) o[mi][ni] = MFMA16(pa[mi], vbr[s][ks][ni], o[mi][ni]);
            __builtin_amdgcn_s_setprio(0);
        }
        f16* dst = s ? att_de : att_se;
#pragma unroll
        for (int mi = 0; mi < 4; ++mi) {
#pragma unroll
            for (int reg = 0; reg < 4; ++reg) {
                int r = 16 * mi + 4 * lg + reg;
                if (r < NTOK) {
#pragma unroll
                    for (int ni = 0; ni < 2; ++ni)
                        dst[(wbase + r) * 384 + h * 32 + 16 * ni + lr] = (f16)o[mi][ni][reg];
                }
            }
        }
    }
}

// ---------------------------------------------------------------------------
extern "C" void kernel_launch(void* const* d_in, const int* in_sizes, int n_in,
                              void* d_out, int out_size, void* d_ws, size_t ws_size,
                              hipStream_t stream) {
    const float* se = (const float*)d_in[0];
    const float* de = (const float*)d_in[1];
    const float* mask = (const float*)d_in[2];
    const float* w_v_se = (const float*)d_in[3];
    const float* b_v_se = (const float*)d_in[4];
    const float* w_qkv = (const float*)d_in[5];
    const float* b_qkv = (const float*)d_in[6];
    const float* w_proj_se = (const float*)d_in[7];
    const float* b_proj_se = (const float*)d_in[8];
    const float* w_proj_de = (const float*)d_in[9];
    const float* b_proj_de = (const float*)d_in[10];
    const float* rpb = (const float*)d_in[11];
    const int* rel_idx = (const int*)d_in[12];

    const size_t SE_ELEMS = (size_t)NBW * NTOK * 384;  // 38,535,168

    char* ws = (char*)d_ws;
    f16* att_se = (f16*)(ws);                   // (100352, 384)
    f16* att_de = (f16*)(ws + 77070336);        // (100352, 384)
    f16* qk_h   = (f16*)(ws + 154140672);       // (100352, 768)
    f16* vse_t  = (f16*)(ws + 308281344);       // (24576, 32, 56)
    f16* vde_t  = (f16*)(ws + 396361728);       // (24576, 32, 56)
    f16* wqkv_h = (f16*)(ws + 484442112);
    f16* wvse_h = (f16*)(ws + 485326848);
    f16* wpse_h = (f16*)(ws + 485621760);
    f16* wpde_h = (f16*)(ws + 485916672);
    float* bm   = (float*)(ws + 486211584);

    cast_weights<<<864, 256, 0, stream>>>(w_qkv, w_v_se, w_proj_se, w_proj_de,
                                          wqkv_h, wvse_h, wpse_h, wpde_h);
    prep_bm<<<48, 64, 0, stream>>>(rpb, rel_idx, mask, bm);

    // qkv = de @ w_qkv^T + b: q,k (scaled q) -> qk_h; v -> vde_t transposed
    gemm_bt<1, true, f16><<<dim3(9, 784), 256, 0, stream>>>((const void*)de, wqkv_h, b_qkv,
                                                            qk_h, vde_t, 1152, 768);
    // v_se = se @ w_v_se^T + b -> vse_t transposed
    gemm_bt<2, true, f16><<<dim3(3, 784), 256, 0, stream>>>((const void*)se, wvse_h, b_v_se,
                                                            (f16*)nullptr, vse_t, 384, 384);

    // attention: 2 (window,head) pairs per block
    attn_kernel<<<NBW * NHEAD / 2, 128, 0, stream>>>(qk_h, vse_t, vde_t, bm, att_se, att_de);

    // projections straight into d_out (f32)
    gemm_bt<0, false, float><<<dim3(3, 784), 256, 0, stream>>>((const void*)att_se, wpse_h, b_proj_se,
                                                               (float*)d_out, nullptr, 384, 384);
    gemm_bt<0, false, float><<<dim3(3, 784), 256, 0, stream>>>((const void*)att_de, wpde_h, b_proj_de,
                                                               (float*)d_out + SE_ELEMS, nullptr, 384, 384);
}